// Round 6
// baseline (961.900 us; speedup 1.0000x reference)
//
#include <hip/hip_runtime.h>

// Instant-NGP style multires hash encoding.
// N=2^20 points, 16 levels, table 2^19 entries x 2 features (float32).
//
// SEMANTICS LEDGER (established R2-R5):
//  - R3 == R4 bit-identical => device IEEE f32 div == faithful f32 emulation.
//    That FAILED => ground truth q-path is NOT plain f32 op-by-op.
//  - R5 exact-rational (== float64 semantics) FAILED => not f64 either.
//  - Everything else (corners, wrap, uint32 hash mod 2^19, weights, layout)
//    is precision-robust; floor/lc f32-vs-f64 flips are continuity-protected
//    (error ~3e-9 << 2e-6 threshold).
//  => Remaining candidate: XLA algebraic-simplifier rewrite of the eager jnp
//     reference: divide-by-constant -> multiply by constant-folded reciprocal:
//       v = RN32( c * RN32(1/res) )   (exact for pow2 res, differs for the
//     11 non-pow2 resolutions at a few % of coords -> sparse hash flips ->
//     the persistent ~1.7-1.8e-4 absmax signature).
//
// q is built as a COMPILE-TIME constexpr table: clang constexpr float math is
// strict IEEE op-by-op (no -ffp-contract=fast FMA fusion, which would corrupt
// c*r+1 on device). Staged to LDS at block start (machinery validated in R4:
// table path was bit-identical to device computation).
//
// RESOLUTIONS trap: int(16 * 32**(9/15)) == 127, NOT 128 (9/15 rounds below
// 0.6 in double; pow -> 7.9999999999999991). Verified analytically with
// <=0.52-ulp pow error margins; levels 32/64/256 robustly safe.

static constexpr int      kNLevels   = 16;
static constexpr unsigned kTableSize = 1u << 19;
static constexpr unsigned kMask      = kTableSize - 1u;
static constexpr unsigned kP1        = 2654435761u;
static constexpr unsigned kP2        = 805459861u;

typedef float v4f __attribute__((ext_vector_type(4)));

// int(16 * 32**(i/15)) with exact Python-double semantics (note 127!)
constexpr int RES_[kNLevels]  = {16, 20, 25, 32, 40, 50, 64, 80,
                                 101, 127, 161, 203, 256, 322, 406, 512};
constexpr int QOFF_[kNLevels] = {0, 16, 36, 61, 93, 133, 183, 247,
                                 327, 428, 555, 716, 919, 1175, 1497, 1903};
static constexpr int kQTot = 2415;  // sum of RES_

// q(c,res) under XLA reciprocal-multiply semantics:
//   r = RN32(1/res); v = RN32(c*r); q = trunc(((v+1)*0.5)*262144)
// constexpr evaluation = strict IEEE f32 per op, no contraction.
constexpr unsigned qval_rcp(int c, int res) {
    const float r = 1.0f / (float)res;          // correctly rounded f32
    const float v = (float)c * r;               // correctly rounded f32 mul
    const float s = ((v + 1.0f) * 0.5f) * 262144.0f;  // +1 rounds; pow2 muls exact
    return (unsigned)s;                          // trunc toward zero
}

struct QTab {
    unsigned v[kQTot];
    constexpr QTab() : v{} {
        int o = 0;
        for (int i = 0; i < kNLevels; ++i) {
            for (int c = 0; c < RES_[i]; ++c) v[o + c] = qval_rcp(c, RES_[i]);
            o += RES_[i];
        }
    }
};
__constant__ QTab QT = QTab();

__global__ __launch_bounds__(256) void hashenc_kernel(
    const float* __restrict__ x,
    const float* __restrict__ tables,
    float* __restrict__ out,
    int N)
{
    __shared__ unsigned sq[kQTot];
    for (int t = threadIdx.x; t < kQTot; t += 256) sq[t] = QT.v[t];
    __syncthreads();

    const int n = blockIdx.x * 256 + threadIdx.x;
    if (n >= N) return;

    float px = x[3 * n + 0];
    float py = x[3 * n + 1];
    float pz = x[3 * n + 2];
    px = fminf(fmaxf(px, -1.0f), 1.0f);
    py = fminf(fmaxf(py, -1.0f), 1.0f);
    pz = fminf(fmaxf(pz, -1.0f), 1.0f);

    float o[2 * kNLevels];

#pragma unroll
    for (int i = 0; i < kNLevels; ++i) {
        const int   res  = RES_[i];
        const float resf = (float)res;
        const unsigned* qt = sq + QOFF_[i];

        // coords, floor, frac (f32, matches reference op-for-op; boundary
        // flips vs higher precision are continuity-protected)
        const float cxf = px * resf, cyf = py * resf, czf = pz * resf;
        const float fx = floorf(cxf), fy = floorf(cyf), fz = floorf(czf);
        const float lx = cxf - fx, ly = cyf - fy, lz = czf - fz;

        // integer corner coords wrapped into [0, res). floor(x*res) in [-res, res].
        const int ix = (int)fx, iy = (int)fy, iz = (int)fz;
        const int cx0 = ix < 0 ? ix + res : (ix >= res ? ix - res : ix);
        const int cy0 = iy < 0 ? iy + res : (iy >= res ? iy - res : iy);
        const int cz0 = iz < 0 ? iz + res : (iz >= res ? iz - res : iz);
        const int cx1 = (cx0 + 1 == res) ? 0 : cx0 + 1;
        const int cy1 = (cy0 + 1 == res) ? 0 : cy0 + 1;
        const int cz1 = (cz0 + 1 == res) ? 0 : cz0 + 1;

        // quantized hash inputs: LDS lookup of the precomputed rcp-mul q
        const unsigned qx0 = qt[cx0], qx1 = qt[cx1];
        const unsigned qy0 = qt[cy0], qy1 = qt[cy1];
        const unsigned qz0 = qt[cz0], qz1 = qt[cz1];

        const unsigned hy0 = qy0 * kP1, hy1 = qy1 * kP1;
        const unsigned hz0 = qz0 * kP2, hz1 = qz1 * kP2;

        // trilinear weights; offset bit2->x(dim0), bit1->y(dim1), bit0->z(dim2)
        const float wx0 = 1.0f - lx, wx1 = lx;
        const float wy0 = 1.0f - ly, wy1 = ly;
        const float wz0 = 1.0f - lz, wz1 = lz;

        unsigned idx[8];
        float    w[8];
#pragma unroll
        for (int m = 0; m < 8; ++m) {
            const unsigned h = ((m & 4) ? qx1 : qx0) +
                               ((m & 2) ? hy1 : hy0) +
                               ((m & 1) ? hz1 : hz0);
            idx[m] = h & kMask;
            w[m] = (((m & 4) ? wx1 : wx0) * ((m & 2) ? wy1 : wy0)) *
                   ((m & 1) ? wz1 : wz0);
        }

        const float2* tb = (const float2*)tables + (size_t)i * kTableSize;

        float2 f[8];
#pragma unroll
        for (int m = 0; m < 8; ++m) f[m] = tb[idx[m]];

        float a0 = 0.0f, a1 = 0.0f;
#pragma unroll
        for (int m = 0; m < 8; ++m) {
            a0 += w[m] * f[m].x;
            a1 += w[m] * f[m].y;
        }
        o[2 * i + 0] = a0;
        o[2 * i + 1] = a1;
    }

    // 32 contiguous floats per point -> 8 x 16B stores
    v4f* op = (v4f*)(out + (size_t)n * (2 * kNLevels));
#pragma unroll
    for (int k = 0; k < 8; ++k) {
        v4f v = {o[4 * k + 0], o[4 * k + 1], o[4 * k + 2], o[4 * k + 3]};
        op[k] = v;
    }
}

extern "C" void kernel_launch(void* const* d_in, const int* in_sizes, int n_in,
                              void* d_out, int out_size, void* d_ws, size_t ws_size,
                              hipStream_t stream) {
    const float* x      = (const float*)d_in[0];
    const float* tables = (const float*)d_in[1];
    float*       out    = (float*)d_out;
    const int N = in_sizes[0] / 3;
    const int blocks = (N + 255) / 256;
    hipLaunchKernelGGL(hashenc_kernel, dim3(blocks), dim3(256), 0, stream,
                       x, tables, out, N);
}